// Round 1
// baseline (666.972 us; speedup 1.0000x reference)
//
#include <hip/hip_runtime.h>
#include <math.h>

// Problem constants (match reference)
constexpr int BATCH = 8;
constexpr int EDIM  = 32;
constexpr int HDIM  = 512;
constexpr int WDIM  = 512;
constexpr int HW    = HDIM * WDIM;          // 262144 pixels per sample
constexpr int NSEG  = 33;                   // NUM_INST + 1 (segment 0 = background)
constexpr int NINST = 32;
constexpr float DELTA_V = 0.5f;
constexpr float TWO_DELTA_D = 3.0f;         // 2 * DELTA_D
constexpr float ALPHA = 1.0f, BETA = 1.0f, GAMMA = 0.001f;

constexpr int TPB  = 256;                   // threads per block
constexpr int PXT  = 4;                     // pixels per thread (float4)
constexpr int TILE = TPB * PXT;             // 1024 pixels per block-tile
constexpr int NTILES = HW / TILE;           // 256 tiles per sample
constexpr int BPS  = 128;                   // blocks per sample (each handles 2 tiles)

// ---------------- workspace zeroing ----------------
__global__ void k_zero(float* __restrict__ p, int n) {
    int i = blockIdx.x * blockDim.x + threadIdx.x;
    if (i < n) p[i] = 0.0f;
}

// ---------------- pass 1: segment sums + counts ----------------
// sums layout: [b][e*NSEG + m]  (matches LDS [e][m], stride 33 -> bank (e+m)%32)
__global__ __launch_bounds__(TPB) void k_segsum(const float* __restrict__ emb,
                                                const int* __restrict__ msk,
                                                float* __restrict__ sums,
                                                float* __restrict__ cnts) {
    __shared__ float s_sum[EDIM * NSEG];
    __shared__ float s_cnt[NSEG];
    const int b = blockIdx.y;
    for (int i = threadIdx.x; i < EDIM * NSEG; i += TPB) s_sum[i] = 0.0f;
    if (threadIdx.x < NSEG) s_cnt[threadIdx.x] = 0.0f;
    __syncthreads();

    const float* embB = emb + (size_t)b * EDIM * HW;
    const int*   mskB = msk + (size_t)b * HW;

    for (int t = blockIdx.x; t < NTILES; t += BPS) {
        const int p0 = t * TILE + threadIdx.x * PXT;
        const int4 m4 = *reinterpret_cast<const int4*>(mskB + p0);
        atomicAdd(&s_cnt[m4.x], 1.0f);
        atomicAdd(&s_cnt[m4.y], 1.0f);
        atomicAdd(&s_cnt[m4.z], 1.0f);
        atomicAdd(&s_cnt[m4.w], 1.0f);
#pragma unroll 8
        for (int e = 0; e < EDIM; ++e) {
            const float4 v = *reinterpret_cast<const float4*>(embB + (size_t)e * HW + p0);
            float* se = s_sum + e * NSEG;
            atomicAdd(&se[m4.x], v.x);
            atomicAdd(&se[m4.y], v.y);
            atomicAdd(&se[m4.z], v.z);
            atomicAdd(&se[m4.w], v.w);
        }
    }
    __syncthreads();
    float* gs = sums + (size_t)b * EDIM * NSEG;
    for (int i = threadIdx.x; i < EDIM * NSEG; i += TPB) {
        const float v = s_sum[i];
        if (v != 0.0f) atomicAdd(&gs[i], v);
    }
    if (threadIdx.x < NSEG) atomicAdd(&cnts[b * NSEG + threadIdx.x], s_cnt[threadIdx.x]);
}

// ---------------- block reduce helper ----------------
__device__ float block_reduce(float v, float* s_red) {
    s_red[threadIdx.x] = v;
    __syncthreads();
    for (int off = 128; off > 0; off >>= 1) {
        if ((int)threadIdx.x < off) s_red[threadIdx.x] += s_red[threadIdx.x + off];
        __syncthreads();
    }
    const float r = s_red[0];
    __syncthreads();
    return r;
}

// ---------------- pass 1.5: means + dist_loss + reg_loss per sample ----------------
// means_t layout: [b][e*NSEG + m]
// partials: [b][3] = {dist_l, reg_l, n_present}
__global__ __launch_bounds__(TPB) void k_means(const float* __restrict__ sums,
                                               const float* __restrict__ cnts,
                                               float* __restrict__ means_t,
                                               float* __restrict__ partials) {
    __shared__ float s_mu[EDIM * NSEG];
    __shared__ float s_cnt[NSEG];
    __shared__ float s_red[TPB];
    const int b = blockIdx.x;
    if (threadIdx.x < NSEG) s_cnt[threadIdx.x] = cnts[b * NSEG + threadIdx.x];
    __syncthreads();
    for (int i = threadIdx.x; i < EDIM * NSEG; i += TPB) {
        const int m = i % NSEG;
        const float mu = sums[(size_t)b * EDIM * NSEG + i] / fmaxf(s_cnt[m], 1.0f);
        s_mu[i] = mu;
        means_t[(size_t)b * EDIM * NSEG + i] = mu;
    }
    __syncthreads();

    // reg loss: instances m=1..32
    float reg = 0.0f, np = 0.0f;
    if (threadIdx.x >= 1 && threadIdx.x < NSEG) {
        float ss = 0.0f;
#pragma unroll
        for (int e = 0; e < EDIM; ++e) {
            const float v = s_mu[e * NSEG + threadIdx.x];
            ss += v * v;
        }
        reg = sqrtf(ss + 1e-12f);
        np = (s_cnt[threadIdx.x] > 0.0f) ? 1.0f : 0.0f;
    }

    // dist loss: 496 unordered pairs among instances 0..31 (mask values i+1)
    float dl = 0.0f;
    for (int p = threadIdx.x; p < (NINST * (NINST - 1)) / 2; p += TPB) {
        int i = 0, pp = p;
        while (pp >= NINST - 1 - i) { pp -= NINST - 1 - i; ++i; }
        const int j = i + 1 + pp;
        float sq = 0.0f;
#pragma unroll
        for (int e = 0; e < EDIM; ++e) {
            const float d = s_mu[e * NSEG + (i + 1)] - s_mu[e * NSEG + (j + 1)];
            sq += d * d;
        }
        const float pd = sqrtf(fmaxf(sq, 1e-12f));
        const float h = fmaxf(TWO_DELTA_D - pd, 0.0f);
        dl += h * h;
    }

    const float dl_t  = block_reduce(dl, s_red);
    const float reg_t = block_reduce(reg, s_red);
    const float np_t  = block_reduce(np, s_red);
    if (threadIdx.x == 0) {
        partials[b * 3 + 0] = dl_t / ((NINST * (NINST - 1)) / 2.0f);
        partials[b * 3 + 1] = reg_t / (float)NINST;
        partials[b * 3 + 2] = fmaxf(np_t, 1.0f);
    }
}

// ---------------- pass 2: hinged variance term ----------------
__global__ __launch_bounds__(TPB) void k_var(const float* __restrict__ emb,
                                             const int* __restrict__ msk,
                                             const float* __restrict__ means_t,
                                             float* __restrict__ varsums) {
    __shared__ float s_mu[EDIM * NSEG];
    __shared__ float s_var[NSEG];
    const int b = blockIdx.y;
    for (int i = threadIdx.x; i < EDIM * NSEG; i += TPB)
        s_mu[i] = means_t[(size_t)b * EDIM * NSEG + i];
    if (threadIdx.x < NSEG) s_var[threadIdx.x] = 0.0f;
    __syncthreads();

    const float* embB = emb + (size_t)b * EDIM * HW;
    const int*   mskB = msk + (size_t)b * HW;

    for (int t = blockIdx.x; t < NTILES; t += BPS) {
        const int p0 = t * TILE + threadIdx.x * PXT;
        const int4 m4 = *reinterpret_cast<const int4*>(mskB + p0);
        float d0 = 0.0f, d1 = 0.0f, d2 = 0.0f, d3 = 0.0f;
#pragma unroll 8
        for (int e = 0; e < EDIM; ++e) {
            const float4 v = *reinterpret_cast<const float4*>(embB + (size_t)e * HW + p0);
            const float* me = s_mu + e * NSEG;
            const float t0 = v.x - me[m4.x]; d0 += t0 * t0;
            const float t1 = v.y - me[m4.y]; d1 += t1 * t1;
            const float t2 = v.z - me[m4.z]; d2 += t2 * t2;
            const float t3 = v.w - me[m4.w]; d3 += t3 * t3;
        }
        if (m4.x > 0) { const float h = fmaxf(sqrtf(d0 + 1e-12f) - DELTA_V, 0.0f); atomicAdd(&s_var[m4.x], h * h); }
        if (m4.y > 0) { const float h = fmaxf(sqrtf(d1 + 1e-12f) - DELTA_V, 0.0f); atomicAdd(&s_var[m4.y], h * h); }
        if (m4.z > 0) { const float h = fmaxf(sqrtf(d2 + 1e-12f) - DELTA_V, 0.0f); atomicAdd(&s_var[m4.z], h * h); }
        if (m4.w > 0) { const float h = fmaxf(sqrtf(d3 + 1e-12f) - DELTA_V, 0.0f); atomicAdd(&s_var[m4.w], h * h); }
    }
    __syncthreads();
    if (threadIdx.x >= 1 && threadIdx.x < NSEG)
        atomicAdd(&varsums[b * NSEG + threadIdx.x], s_var[threadIdx.x]);
}

// ---------------- final: combine losses ----------------
__global__ void k_final(const float* __restrict__ varsums,
                        const float* __restrict__ cnts,
                        const float* __restrict__ partials,
                        float* __restrict__ out) {
    const int l = threadIdx.x;  // 64 threads, one wave
    float var_acc = 0.0f, dist_acc = 0.0f, reg_acc = 0.0f;
    for (int b = 0; b < BATCH; ++b) {
        float v = 0.0f;
        if (l >= 1 && l < NSEG) {
            const float c = cnts[b * NSEG + l];
            if (c > 0.0f) v = varsums[b * NSEG + l] / fmaxf(c, 1.0f);
        }
#pragma unroll
        for (int off = 32; off > 0; off >>= 1) v += __shfl_xor(v, off);
        var_acc  += v / partials[b * 3 + 2];
        dist_acc += partials[b * 3 + 0];
        reg_acc  += partials[b * 3 + 1];
    }
    if (l == 0) {
        const float var  = var_acc  / (float)BATCH;
        const float dist = dist_acc / (float)BATCH;
        const float reg  = reg_acc  / (float)BATCH;
        out[0] = ALPHA * var + BETA * dist + GAMMA * reg;
        out[1] = var;
        out[2] = dist;
        out[3] = reg;
    }
}

extern "C" void kernel_launch(void* const* d_in, const int* in_sizes, int n_in,
                              void* d_out, int out_size, void* d_ws, size_t ws_size,
                              hipStream_t stream) {
    const float* emb = (const float*)d_in[0];
    const int*   msk = (const int*)d_in[1];
    float* out = (float*)d_out;

    float* ws       = (float*)d_ws;
    float* sums     = ws;                                  // B*E*NSEG = 8448
    float* cnts     = sums + BATCH * EDIM * NSEG;          // B*NSEG   = 264
    float* varsums  = cnts + BATCH * NSEG;                 // B*NSEG   = 264
    float* means_t  = varsums + BATCH * NSEG;              // B*E*NSEG = 8448
    float* partials = means_t + BATCH * EDIM * NSEG;       // B*3      = 24

    const int nzero = BATCH * EDIM * NSEG + 2 * BATCH * NSEG;   // accumulators only
    k_zero<<<(nzero + TPB - 1) / TPB, TPB, 0, stream>>>(ws, nzero);

    dim3 grid(BPS, BATCH);
    k_segsum<<<grid, TPB, 0, stream>>>(emb, msk, sums, cnts);
    k_means<<<BATCH, TPB, 0, stream>>>(sums, cnts, means_t, partials);
    k_var<<<grid, TPB, 0, stream>>>(emb, msk, means_t, varsums);
    k_final<<<1, 64, 0, stream>>>(varsums, cnts, partials, out);
}